// Round 7
// baseline (214.088 us; speedup 1.0000x reference)
//
#include <hip/hip_runtime.h>
#include <hip/hip_bf16.h>

typedef __bf16 bf16_t;
typedef __bf16 bf16x8 __attribute__((ext_vector_type(8)));
typedef float  f32x4  __attribute__((ext_vector_type(4)));

#define MFMA16(a, b, c) __builtin_amdgcn_mfma_f32_16x16x32_bf16((a), (b), (c), 0, 0, 0)

constexpr int Bc = 4, Lc = 2048, Hc = 8, Dc = 64;
constexpr int HD = Hc * Dc;            // 512
constexpr int TRAINc = 1536;
constexpr int ROWS_BLK = 64;           // q rows per workgroup (4 waves x 16)
constexpr int KT = 64;                 // keys per k-tile

constexpr int PREPK_BLOCKS = (int)((size_t)Bc * Lc * Hc * Dc / 8 / 256);  // 2048

// ---------------- fused prep: K cast + V transpose in one launch ----------------
__global__ void prep_fused(const float* __restrict__ K, bf16_t* __restrict__ Kb,
                           const float* __restrict__ V, bf16_t* __restrict__ Vt) {
  // [64][64] tile; 8-elem (16B) chunk c of row r stored at chunk c ^ (r>>3):
  // column reads then spread 64 lanes over all 32 banks (2/bank = free).
  __shared__ bf16_t T[64][64];
  const int t = (int)threadIdx.x;

  if ((int)blockIdx.x < PREPK_BLOCKS) {
    size_t g = ((size_t)blockIdx.x * 256 + t) * 8;
    float4 a = *(const float4*)(K + g);
    float4 b = *(const float4*)(K + g + 4);
    bf16x8 v;
    v[0] = (bf16_t)a.x; v[1] = (bf16_t)a.y; v[2] = (bf16_t)a.z; v[3] = (bf16_t)a.w;
    v[4] = (bf16_t)b.x; v[5] = (bf16_t)b.y; v[6] = (bf16_t)b.z; v[7] = (bf16_t)b.w;
    *(bf16x8*)(Kb + g) = v;
    return;
  }

  const int bid = (int)blockIdx.x - PREPK_BLOCKS;
  const int kt = bid & 31, h = (bid >> 5) & 7, b = bid >> 8;
  {
    int kl = t >> 2, dp = (t & 3) << 4;
    const float* s = V + ((size_t)(b * Lc + kt * 64 + kl) * Hc + h) * Dc + dp;
    bf16x8 v0, v1;
    float4 f;
    f = *(const float4*)(s);      v0[0]=(bf16_t)f.x; v0[1]=(bf16_t)f.y; v0[2]=(bf16_t)f.z; v0[3]=(bf16_t)f.w;
    f = *(const float4*)(s + 4);  v0[4]=(bf16_t)f.x; v0[5]=(bf16_t)f.y; v0[6]=(bf16_t)f.z; v0[7]=(bf16_t)f.w;
    f = *(const float4*)(s + 8);  v1[0]=(bf16_t)f.x; v1[1]=(bf16_t)f.y; v1[2]=(bf16_t)f.z; v1[3]=(bf16_t)f.w;
    f = *(const float4*)(s + 12); v1[4]=(bf16_t)f.x; v1[5]=(bf16_t)f.y; v1[6]=(bf16_t)f.z; v1[7]=(bf16_t)f.w;
    const int x = kl >> 3;
    const int c0 = dp >> 3;
    *(bf16x8*)&T[kl][(c0 ^ x) << 3]       = v0;
    *(bf16x8*)&T[kl][((c0 + 1) ^ x) << 3] = v1;
  }
  __syncthreads();
  {
    int d = t >> 2, kp = (t & 3) << 4;
    const int xa = kp >> 3;
    const int xb = xa + 1;
    const int lo = d & 7, hi = d >> 3;
    const int x0 = ((hi ^ xa) << 3) + lo;
    const int x1 = ((hi ^ xb) << 3) + lo;
    bf16x8 o0, o1;
#pragma unroll
    for (int i = 0; i < 8; ++i) { o0[i] = T[kp + i][x0]; o1[i] = T[kp + 8 + i][x1]; }
    bf16_t* dst = Vt + ((size_t)((b * Hc + h) * Dc + d)) * Lc + kt * 64 + kp;
    *(bf16x8*)dst = o0;
    *(bf16x8*)(dst + 8) = o1;
  }
}

// ---------------- main attention ----------------
static __device__ __forceinline__ bf16x8 mk8(unsigned w0, unsigned w1,
                                             unsigned w2, unsigned w3) {
  union { unsigned u[4]; bf16x8 v; } x;
  x.u[0] = w0; x.u[1] = w1; x.u[2] = w2; x.u[3] = w3;
  return x.v;
}

// No LDS, no barriers: K/V per (b,h) slice is 256 KB bf16 -> L2/L1-resident.
// Each wave loads its MFMA fragments DIRECTLY from global (16 x dwordx4/phase,
// 16x64B coalesced segments) and free-runs; 16 independent waves/CU hide L2
// latency. Softmax stays fully in-register (swapped QK^T + cvt_pk + permlane).
__global__ __launch_bounds__(256, 4)
void continual_attn(const float* __restrict__ Qg, const bf16_t* __restrict__ Kb,
                    const bf16_t* __restrict__ Vt, const int* __restrict__ ATT,
                    float* __restrict__ OUT)
{
  const int bid  = blockIdx.x;
  // balanced mapping: CU-group a (= (bid>>5)&7 under round-robin dispatch) gets
  // qblks {24+a, 15-g..., } -> tile sums spread 57..64 (was 50..71).
  const int g    = bid >> 5;
  int qblk;
  if (g < 8)       qblk = 24 + g;     // test blocks (heaviest) dispatch first
  else if (g < 16) qblk = 15 - g;     // 7..0
  else if (g < 24) qblk = g - 8;      // 8..15
  else             qblk = 47 - g;     // 23..16
  const int h    = bid & 7;
  const int b    = (bid >> 3) & 3;
  const int q0   = qblk * ROWS_BLK;

  const int tid  = (int)threadIdx.x;
  const int wave = tid >> 6;
  const int lane = tid & 63;
  const int quad = lane >> 4;
  const int col  = lane & 15;
  const int qw   = q0 + wave * 16;

  const size_t bhQ = (size_t)b * Lc * HD + (size_t)h * Dc;

  // per-lane fragment base pointers (key/d offsets added per phase)
  // K frag A-layout: lane holds K[key=kg*16+col][d=quad*8+j]
  const bf16_t* kfb = Kb + bhQ + (size_t)col * HD + quad * 8;
  // V frag B-layout: lane holds V[key=k0+quad*8+j][d=t*16+col] from Vt[d][key]
  const bf16_t* vfb = Vt + ((size_t)((b * Hc + h) * Dc) + col) * Lc + quad * 8;

  // ---- Q fragments (row=col, k=quad*8+j), prescaled by 1/8 * log2(e) ----
  bf16x8 aq[2];
  {
    const float* qp = Qg + bhQ + (size_t)(qw + col) * HD + quad * 8;
    const float SC = 0.125f * 1.44269504f;
#pragma unroll
    for (int t = 0; t < 2; ++t) {
      float4 lo = *(const float4*)(qp + t * 32);
      float4 hi = *(const float4*)(qp + t * 32 + 4);
      bf16x8 v;
      v[0] = (bf16_t)(lo.x * SC); v[1] = (bf16_t)(lo.y * SC);
      v[2] = (bf16_t)(lo.z * SC); v[3] = (bf16_t)(lo.w * SC);
      v[4] = (bf16_t)(hi.x * SC); v[5] = (bf16_t)(hi.y * SC);
      v[6] = (bf16_t)(hi.z * SC); v[7] = (bf16_t)(hi.w * SC);
      aq[t] = v;
    }
  }

  // ---- per-lane mask scalars (this lane's q-row is q = qw + col) ----
  const bool testblk = (q0 >= TRAINc);
  const int qi = qw + col;
  int kendL, cstartL;
  if (testblk) {
    kendL   = ATT[b * 64 + ((qi - TRAINc) >> 3)] + 1;
    cstartL = qi & ~7;
  } else {
    kendL   = qi + 1;
    cstartL = 0;
  }

  int ntA, ndiag, kfull_end;
  if (testblk) {
    int c0 = (q0 - TRAINc) >> 3;
    int amax = 0, amin = 0x7fffffff;
#pragma unroll
    for (int i = 0; i < 8; ++i) {
      int a = ATT[b * 64 + c0 + i];
      amax = (a > amax) ? a : amax;
      amin = (a < amin) ? a : amin;
    }
    ntA = (amax >> 6) + 1;   // 64-wide tiles covering [0, amax]
    ndiag = 1;               // own 64-wide diagonal block at k0=q0
    kfull_end = amin + 1;
  } else {
    ntA = qblk + 1;          // causal tiles covering [0, q0+64)
    ndiag = 0;
    kfull_end = q0 + 1;
  }
  const int ntot = ntA + ndiag;

  float ls[4] = {0.f, 0.f, 0.f, 0.f};   // ILP partials; all belong to q = qw+col
  f32x4 o[4] = {{0,0,0,0},{0,0,0,0},{0,0,0,0},{0,0,0,0}};

  for (int ti = 0; ti < ntot; ++ti) {
    const int k0 = (ti < ntA) ? ti * KT : q0 + (ti - ntA) * KT;

    // ---- fragment loads straight from global (L2/L1-cached) ----
    // K issued first; QK^T waits only on these, V stays in flight through softmax.
    bf16x8 kf0[4], kf1[4], vf0[4], vf1[4];
#pragma unroll
    for (int kg = 0; kg < 4; ++kg) {
      const bf16_t* p = kfb + (size_t)(k0 + kg * 16) * HD;
      kf0[kg] = *(const bf16x8*)p;
      kf1[kg] = *(const bf16x8*)(p + 32);
    }
#pragma unroll
    for (int t = 0; t < 4; ++t) {
      const bf16_t* p = vfb + (size_t)(t * 16) * Lc + k0;
      vf0[t] = *(const bf16x8*)p;
      vf1[t] = *(const bf16x8*)(p + 32);
    }

    // ---- S^T = K Q^T  (swapped; sf[kg][r] = S[key=k0+kg*16+quad*4+r][q=qi]) ----
    f32x4 sf[4] = {{0,0,0,0},{0,0,0,0},{0,0,0,0},{0,0,0,0}};
    __builtin_amdgcn_s_setprio(1);
#pragma unroll
    for (int kg = 0; kg < 4; ++kg) {
      sf[kg] = MFMA16(kf0[kg], aq[0], sf[kg]);
      sf[kg] = MFMA16(kf1[kg], aq[1], sf[kg]);
    }
    __builtin_amdgcn_s_setprio(0);

    const int mode = (ti >= ntA) ? 2 : ((k0 + KT <= kfull_end) ? 0 : 1);
    if (mode == 1) {
#pragma unroll
      for (int kg = 0; kg < 4; ++kg) {
        const int kv = k0 + kg * 16 + quad * 4;
#pragma unroll
        for (int r = 0; r < 4; ++r)
          if (kv + r >= kendL) sf[kg][r] = -1e30f;
      }
    } else if (mode == 2) {
#pragma unroll
      for (int kg = 0; kg < 4; ++kg) {
        const int kv = k0 + kg * 16 + quad * 4;
#pragma unroll
        for (int r = 0; r < 4; ++r)
          if (kv + r < cstartL || kv + r > qi) sf[kg][r] = -1e30f;
      }
    }

    // ---- exp2 (fixed-max: logits*log2e bounded, exp2 fp32/bf16-safe) ----
    float pvv[4][4];
#pragma unroll
    for (int kg = 0; kg < 4; ++kg)
#pragma unroll
      for (int r = 0; r < 4; ++r) {
        float p = __builtin_amdgcn_exp2f(sf[kg][r]);
        pvv[kg][r] = p;
        ls[r] += p;
      }

    // ---- pack to bf16 pairs: Dw[kg][d] = (key 16kg+4quad+2d, +2d+1) for q=col ----
    unsigned Dw[4][2];
#pragma unroll
    for (int kg = 0; kg < 4; ++kg)
#pragma unroll
      for (int d = 0; d < 2; ++d)
        asm("v_cvt_pk_bf16_f32 %0, %1, %2"
            : "=v"(Dw[kg][d]) : "v"(pvv[kg][2 * d]), "v"(pvv[kg][2 * d + 1]));

    // ---- quad redistribution via permlane swaps (in-register P transpose) ----
    unsigned a0 = Dw[0][0], b0 = Dw[1][0];
    asm volatile("v_permlane32_swap_b32 %0, %1" : "+v"(a0), "+v"(b0));
    asm volatile("v_permlane16_swap_b32 %0, %1" : "+v"(a0), "+v"(b0));
    unsigned a1 = Dw[0][1], b1 = Dw[1][1];
    asm volatile("v_permlane32_swap_b32 %0, %1" : "+v"(a1), "+v"(b1));
    asm volatile("v_permlane16_swap_b32 %0, %1" : "+v"(a1), "+v"(b1));
    unsigned a2 = Dw[2][0], b2 = Dw[3][0];
    asm volatile("v_permlane32_swap_b32 %0, %1" : "+v"(a2), "+v"(b2));
    asm volatile("v_permlane16_swap_b32 %0, %1" : "+v"(a2), "+v"(b2));
    unsigned a3 = Dw[2][1], b3 = Dw[3][1];
    asm volatile("v_permlane32_swap_b32 %0, %1" : "+v"(a3), "+v"(b3));
    asm volatile("v_permlane16_swap_b32 %0, %1" : "+v"(a3), "+v"(b3));

    // pa0 holds P[q=col][keys quad*8+0..7], pa1 the same for keys 32..63
    bf16x8 pa0 = mk8(a0, a1, b0, b1);
    bf16x8 pa1 = mk8(a2, a3, b2, b3);

    // ---- O += P V  (V fragments arrived from global during softmax) ----
    __builtin_amdgcn_s_setprio(1);
#pragma unroll
    for (int t = 0; t < 4; ++t) {
      o[t] = MFMA16(pa0, vf0[t], o[t]);
      o[t] = MFMA16(pa1, vf1[t], o[t]);
    }
    __builtin_amdgcn_s_setprio(0);
  }

  // ---- epilogue: denom for q=qw+col lives per-lane; reduce over quads,
  //      then fetch per-output-row denominators with shfl, normalize, store ----
  float rs = (ls[0] + ls[1]) + (ls[2] + ls[3]);
  rs += __shfl_xor(rs, 16);
  rs += __shfl_xor(rs, 32);
#pragma unroll
  for (int r = 0; r < 4; ++r) {
    float dr = __shfl(rs, quad * 4 + r);   // lane (quad*4+r) has denom for q=qw+quad*4+r
    float inv = 1.f / dr;
    int qo = qw + quad * 4 + r;
    float* op = OUT + ((size_t)b * Lc + qo) * HD + (size_t)h * Dc + col;
    op[0]  = o[0][r] * inv;
    op[16] = o[1][r] * inv;
    op[32] = o[2][r] * inv;
    op[48] = o[3][r] * inv;
  }
}

extern "C" void kernel_launch(void* const* d_in, const int* in_sizes, int n_in,
                              void* d_out, int out_size, void* d_ws, size_t ws_size,
                              hipStream_t stream) {
  const float* Q   = (const float*)d_in[0];
  const float* K   = (const float*)d_in[1];
  const float* V   = (const float*)d_in[2];
  const int*   ATT = (const int*)d_in[3];
  float* OUT = (float*)d_out;
  (void)in_sizes; (void)n_in; (void)out_size; (void)ws_size;

  const size_t NE = (size_t)Bc * Lc * Hc * Dc;
  bf16_t* Kb = (bf16_t*)d_ws;
  bf16_t* Vt = Kb + NE;

  prep_fused<<<dim3((unsigned)(PREPK_BLOCKS + Bc * Hc * (Lc / 64))), dim3(256), 0, stream>>>(K, Kb, V, Vt);
  continual_attn<<<dim3(Bc * Hc * (Lc / ROWS_BLK)), dim3(256), 0, stream>>>(Q, Kb, Vt, ATT, OUT);
}

// Round 8
// 129.107 us; speedup vs baseline: 1.6582x; 1.6582x over previous
//
#include <hip/hip_runtime.h>
#include <hip/hip_bf16.h>

typedef __bf16 bf16_t;
typedef __bf16 bf16x8 __attribute__((ext_vector_type(8)));
typedef float  f32x4  __attribute__((ext_vector_type(4)));

#define MFMA16(a, b, c) __builtin_amdgcn_mfma_f32_16x16x32_bf16((a), (b), (c), 0, 0, 0)

constexpr int Bc = 4, Lc = 2048, Hc = 8, Dc = 64;
constexpr int HD = Hc * Dc;            // 512
constexpr int TRAINc = 1536;
constexpr int ROWS_BLK = 64;           // q rows per workgroup (4 waves x 16)
constexpr int KT = 64;                 // keys per k-tile

constexpr int PREPK_BLOCKS = (int)((size_t)Bc * Lc * Hc * Dc / 8 / 256);  // 2048

// ---------------- fused prep: K cast + V transpose in one launch ----------------
__global__ void prep_fused(const float* __restrict__ K, bf16_t* __restrict__ Kb,
                           const float* __restrict__ V, bf16_t* __restrict__ Vt) {
  __shared__ bf16_t T[64][64];
  const int t = (int)threadIdx.x;

  if ((int)blockIdx.x < PREPK_BLOCKS) {
    size_t g = ((size_t)blockIdx.x * 256 + t) * 8;
    float4 a = *(const float4*)(K + g);
    float4 b = *(const float4*)(K + g + 4);
    bf16x8 v;
    v[0] = (bf16_t)a.x; v[1] = (bf16_t)a.y; v[2] = (bf16_t)a.z; v[3] = (bf16_t)a.w;
    v[4] = (bf16_t)b.x; v[5] = (bf16_t)b.y; v[6] = (bf16_t)b.z; v[7] = (bf16_t)b.w;
    *(bf16x8*)(Kb + g) = v;
    return;
  }

  const int bid = (int)blockIdx.x - PREPK_BLOCKS;
  const int kt = bid & 31, h = (bid >> 5) & 7, b = bid >> 8;
  {
    int kl = t >> 2, dp = (t & 3) << 4;
    const float* s = V + ((size_t)(b * Lc + kt * 64 + kl) * Hc + h) * Dc + dp;
    bf16x8 v0, v1;
    float4 f;
    f = *(const float4*)(s);      v0[0]=(bf16_t)f.x; v0[1]=(bf16_t)f.y; v0[2]=(bf16_t)f.z; v0[3]=(bf16_t)f.w;
    f = *(const float4*)(s + 4);  v0[4]=(bf16_t)f.x; v0[5]=(bf16_t)f.y; v0[6]=(bf16_t)f.z; v0[7]=(bf16_t)f.w;
    f = *(const float4*)(s + 8);  v1[0]=(bf16_t)f.x; v1[1]=(bf16_t)f.y; v1[2]=(bf16_t)f.z; v1[3]=(bf16_t)f.w;
    f = *(const float4*)(s + 12); v1[4]=(bf16_t)f.x; v1[5]=(bf16_t)f.y; v1[6]=(bf16_t)f.z; v1[7]=(bf16_t)f.w;
    const int x = kl >> 3;
    const int c0 = dp >> 3;
    *(bf16x8*)&T[kl][(c0 ^ x) << 3]       = v0;
    *(bf16x8*)&T[kl][((c0 + 1) ^ x) << 3] = v1;
  }
  __syncthreads();
  {
    int d = t >> 2, kp = (t & 3) << 4;
    const int xa = kp >> 3;
    const int xb = xa + 1;
    const int lo = d & 7, hi = d >> 3;
    const int x0 = ((hi ^ xa) << 3) + lo;
    const int x1 = ((hi ^ xb) << 3) + lo;
    bf16x8 o0, o1;
#pragma unroll
    for (int i = 0; i < 8; ++i) { o0[i] = T[kp + i][x0]; o1[i] = T[kp + 8 + i][x1]; }
    bf16_t* dst = Vt + ((size_t)((b * Hc + h) * Dc + d)) * Lc + kt * 64 + kp;
    *(bf16x8*)dst = o0;
    *(bf16x8*)(dst + 8) = o1;
  }
}

// ---------------- main attention ----------------
static __device__ __forceinline__ void load16(const bf16_t* g, bf16_t* l) {
  __builtin_amdgcn_global_load_lds(
      (const __attribute__((address_space(1))) unsigned int*)g,
      (__attribute__((address_space(3))) unsigned int*)l, 16, 0, 0);
}

static __device__ __forceinline__ bf16x8 mk8(unsigned w0, unsigned w1,
                                             unsigned w2, unsigned w3) {
  union { unsigned u[4]; bf16x8 v; } x;
  x.u[0] = w0; x.u[1] = w1; x.u[2] = w2; x.u[3] = w3;
  return x.v;
}

// R6 base (LDS staging + in-register swapped-QK^T softmax) + 2-stage software
// pipeline: phase t runs QK^T(t+1) [MFMA+DS] concurrently with softmax(t)
// [VALU] and PV(t) [MFMA+DS] in one branchless basic block, breaking the
// serial per-tile dependency chain. 2-buffer K/V still suffices (QKT pulled
// one phase early; every LDS overwrite is barrier-separated from its reader).
__global__ __launch_bounds__(256, 4)
void continual_attn(const float* __restrict__ Qg, const bf16_t* __restrict__ Kb,
                    const bf16_t* __restrict__ Vt, const int* __restrict__ ATT,
                    float* __restrict__ OUT)
{
  // [key][64] / [d][64] rows of 128B; 16B slot s of row r holds logical chunk s^(r&7)
  __shared__ __align__(16) bf16_t Klds[2][KT * 64];   // 2 x 8 KB
  __shared__ __align__(16) bf16_t Vlds[2][Dc * KT];   // 2 x 8 KB  (total 32 KB)

  const int bid  = blockIdx.x;
  // balanced mapping: CU-group gets qblks {24+a, 7-a, 8+a, 23-a} -> tile sums 57..64
  const int g    = bid >> 5;
  int qblk;
  if (g < 8)       qblk = 24 + g;     // test blocks (heaviest) dispatch first
  else if (g < 16) qblk = 15 - g;     // 7..0
  else if (g < 24) qblk = g - 8;      // 8..15
  else             qblk = 47 - g;     // 23..16
  const int h    = bid & 7;
  const int b    = (bid >> 3) & 3;
  const int q0   = qblk * ROWS_BLK;

  const int tid  = (int)threadIdx.x;
  const int wave = tid >> 6;
  const int lane = tid & 63;
  const int quad = lane >> 4;
  const int col  = lane & 15;
  const int qw   = q0 + wave * 16;

  const size_t bhQ = (size_t)b * Lc * HD + (size_t)h * Dc;

  // staging source pointers (per-lane; k-offset added per tile). XOR swizzle on source.
  const int kr = tid >> 3;                                   // row 0..31
  const bf16_t* ksrcA = Kb + bhQ + (size_t)kr * HD + (((tid & 7) ^ (kr & 7)) << 3);
  const bf16_t* vsrcA = Vt + ((size_t)((b * Hc + h) * Dc + kr)) * Lc + (((tid & 7) ^ (kr & 7)) << 3);
  const bf16_t* vsrcB = vsrcA + (size_t)32 * Lc;             // d rows 32..63, same swizzle

  // ---- Q fragments (row=col, k=quad*8+j), prescaled by 1/8 * log2(e) ----
  bf16x8 aq[2];
  {
    const float* qp = Qg + bhQ + (size_t)(qw + col) * HD + quad * 8;
    const float SC = 0.125f * 1.44269504f;
#pragma unroll
    for (int t = 0; t < 2; ++t) {
      float4 lo = *(const float4*)(qp + t * 32);
      float4 hi = *(const float4*)(qp + t * 32 + 4);
      bf16x8 v;
      v[0] = (bf16_t)(lo.x * SC); v[1] = (bf16_t)(lo.y * SC);
      v[2] = (bf16_t)(lo.z * SC); v[3] = (bf16_t)(lo.w * SC);
      v[4] = (bf16_t)(hi.x * SC); v[5] = (bf16_t)(hi.y * SC);
      v[6] = (bf16_t)(hi.z * SC); v[7] = (bf16_t)(hi.w * SC);
      aq[t] = v;
    }
  }

  // ---- per-lane mask scalars (this lane's q-row is q = qw + col) ----
  const bool testblk = (q0 >= TRAINc);
  const int qi = qw + col;
  int kendL, cstartL;
  if (testblk) {
    kendL   = ATT[b * 64 + ((qi - TRAINc) >> 3)] + 1;
    cstartL = qi & ~7;
  } else {
    kendL   = qi + 1;
    cstartL = 0;
  }

  int ntA, ndiag, kfull_end;
  if (testblk) {
    int c0 = (q0 - TRAINc) >> 3;
    int amax = 0, amin = 0x7fffffff;
#pragma unroll
    for (int i = 0; i < 8; ++i) {
      int a = ATT[b * 64 + c0 + i];
      amax = (a > amax) ? a : amax;
      amin = (a < amin) ? a : amin;
    }
    ntA = (amax >> 6) + 1;   // 64-wide tiles covering [0, amax]
    ndiag = 1;               // own 64-wide diagonal block at k0=q0
    kfull_end = amin + 1;
  } else {
    ntA = qblk + 1;          // causal tiles covering [0, q0+64)
    ndiag = 0;
    kfull_end = q0 + 1;
  }
  const int ntot = ntA + ndiag;

  float ls[4] = {0.f, 0.f, 0.f, 0.f};
  f32x4 o[4] = {{0,0,0,0},{0,0,0,0},{0,0,0,0},{0,0,0,0}};

  const int cA = ((quad ^ (col & 7)) << 3);   // swizzled 16B slot for k/d 0..31

  // tile index -> k0 (clamped to valid range for branchless over-run phases)
  auto tk0 = [&](int t) {
    int tc = (t < ntot) ? t : (ntot - 1);
    return (tc < ntA) ? tc * KT : q0 + (tc - ntA) * KT;
  };

  // ---- prologue: stage K(0); QKT(0); stage V(0), K(1) under QKT's shadow ----
  {
    load16(ksrcA, Klds[0] + wave * 512);
    load16(ksrcA + (size_t)32 * HD, Klds[0] + 2048 + wave * 512);
  }
  __syncthreads();
  {
    const int k1p = tk0(1);
    load16(vsrcA, Vlds[0] + wave * 512);
    load16(vsrcB, Vlds[0] + 2048 + wave * 512);
    load16(ksrcA + (size_t)k1p * HD, Klds[1] + wave * 512);
    load16(ksrcA + (size_t)(k1p + 32) * HD, Klds[1] + 2048 + wave * 512);
  }

  f32x4 sfA[4];   // masked S^T of tile t (valid at loop top)
  {
    const bf16_t* kb = Klds[0];
    f32x4 sf[4] = {{0,0,0,0},{0,0,0,0},{0,0,0,0},{0,0,0,0}};
#pragma unroll
    for (int kg = 0; kg < 4; ++kg) {
      const bf16_t* krow = kb + (kg * 16 + col) * 64;
      bf16x8 k0f = *(const bf16x8*)(krow + cA);
      bf16x8 k1f = *(const bf16x8*)(krow + (cA ^ 32));
      sf[kg] = MFMA16(k0f, aq[0], sf[kg]);
      sf[kg] = MFMA16(k1f, aq[1], sf[kg]);
    }
    const int mode0 = (0 >= ntA) ? 2 : ((KT <= kfull_end) ? 0 : 1);
    if (mode0 == 1) {
#pragma unroll
      for (int kg = 0; kg < 4; ++kg) {
        const int kv = kg * 16 + quad * 4;
#pragma unroll
        for (int r = 0; r < 4; ++r)
          if (kv + r >= kendL) sf[kg][r] = -1e30f;
      }
    } else if (mode0 == 2) {
#pragma unroll
      for (int kg = 0; kg < 4; ++kg) {
        const int kv = kg * 16 + quad * 4;
#pragma unroll
        for (int r = 0; r < 4; ++r)
          if (kv + r < cstartL || kv + r > qi) sf[kg][r] = -1e30f;
      }
    }
#pragma unroll
    for (int i = 0; i < 4; ++i) sfA[i] = sf[i];
  }

  for (int ti = 0; ti < ntot; ++ti) {
    __syncthreads();   // drains vmcnt: K(t+1), V(t) staged last phase are ready

    // ---- stage K(t+2) -> Klds[ti&1], V(t+1) -> Vlds[(ti+1)&1] (clamped) ----
    {
      const int k2 = tk0(ti + 2);
      const int k1 = tk0(ti + 1);
      bf16_t* kd = Klds[ti & 1];
      bf16_t* vd = Vlds[(ti + 1) & 1];
      load16(ksrcA + (size_t)k2 * HD, kd + wave * 512);
      load16(ksrcA + (size_t)(k2 + 32) * HD, kd + 2048 + wave * 512);
      load16(vsrcA + k1, vd + wave * 512);
      load16(vsrcB + k1, vd + 2048 + wave * 512);
    }

    // ---- QK^T(t+1) from Klds[(ti+1)&1]  (overlaps softmax(t) below) ----
    f32x4 sfB[4] = {{0,0,0,0},{0,0,0,0},{0,0,0,0},{0,0,0,0}};
    {
      const int t1 = (ti + 1 < ntot) ? ti + 1 : ntot - 1;
      const int k1 = tk0(ti + 1);
      const bf16_t* kb = Klds[(ti + 1) & 1];
#pragma unroll
      for (int kg = 0; kg < 4; ++kg) {
        const bf16_t* krow = kb + (kg * 16 + col) * 64;
        bf16x8 k0f = *(const bf16x8*)(krow + cA);
        bf16x8 k1f = *(const bf16x8*)(krow + (cA ^ 32));
        sfB[kg] = MFMA16(k0f, aq[0], sfB[kg]);
        sfB[kg] = MFMA16(k1f, aq[1], sfB[kg]);
      }
      const int mode = (t1 >= ntA) ? 2 : ((k1 + KT <= kfull_end) ? 0 : 1);
      if (mode == 1) {
#pragma unroll
        for (int kg = 0; kg < 4; ++kg) {
          const int kv = k1 + kg * 16 + quad * 4;
#pragma unroll
          for (int r = 0; r < 4; ++r)
            if (kv + r >= kendL) sfB[kg][r] = -1e30f;
        }
      } else if (mode == 2) {
#pragma unroll
        for (int kg = 0; kg < 4; ++kg) {
          const int kv = k1 + kg * 16 + quad * 4;
#pragma unroll
          for (int r = 0; r < 4; ++r)
            if (kv + r < cstartL || kv + r > qi) sfB[kg][r] = -1e30f;
        }
      }
    }

    // ---- softmax(t): exp2 + pack + permlane (pure VALU, overlaps QKT above) ----
    float pvv[4][4];
#pragma unroll
    for (int kg = 0; kg < 4; ++kg)
#pragma unroll
      for (int r = 0; r < 4; ++r) {
        float p = __builtin_amdgcn_exp2f(sfA[kg][r]);
        pvv[kg][r] = p;
        ls[r] += p;
      }

    unsigned Dw[4][2];
#pragma unroll
    for (int kg = 0; kg < 4; ++kg)
#pragma unroll
      for (int d = 0; d < 2; ++d)
        asm("v_cvt_pk_bf16_f32 %0, %1, %2"
            : "=v"(Dw[kg][d]) : "v"(pvv[kg][2 * d]), "v"(pvv[kg][2 * d + 1]));

    unsigned a0 = Dw[0][0], b0 = Dw[1][0];
    asm volatile("v_permlane32_swap_b32 %0, %1" : "+v"(a0), "+v"(b0));
    asm volatile("v_permlane16_swap_b32 %0, %1" : "+v"(a0), "+v"(b0));
    unsigned a1 = Dw[0][1], b1 = Dw[1][1];
    asm volatile("v_permlane32_swap_b32 %0, %1" : "+v"(a1), "+v"(b1));
    asm volatile("v_permlane16_swap_b32 %0, %1" : "+v"(a1), "+v"(b1));
    unsigned a2 = Dw[2][0], b2 = Dw[3][0];
    asm volatile("v_permlane32_swap_b32 %0, %1" : "+v"(a2), "+v"(b2));
    asm volatile("v_permlane16_swap_b32 %0, %1" : "+v"(a2), "+v"(b2));
    unsigned a3 = Dw[2][1], b3 = Dw[3][1];
    asm volatile("v_permlane32_swap_b32 %0, %1" : "+v"(a3), "+v"(b3));
    asm volatile("v_permlane16_swap_b32 %0, %1" : "+v"(a3), "+v"(b3));

    bf16x8 pa0 = mk8(a0, a1, b0, b1);
    bf16x8 pa1 = mk8(a2, a3, b2, b3);

    // ---- O += P V  from Vlds[ti&1] ----
    const bf16_t* vbuf = Vlds[ti & 1];
    __builtin_amdgcn_s_setprio(1);
#pragma unroll
    for (int t = 0; t < 4; ++t) {
      const bf16_t* vrow = vbuf + (t * 16 + col) * 64;
      bf16x8 v0 = *(const bf16x8*)(vrow + cA);
      bf16x8 v1 = *(const bf16x8*)(vrow + (cA ^ 32));
      o[t] = MFMA16(pa0, v0, o[t]);
      o[t] = MFMA16(pa1, v1, o[t]);
    }
    __builtin_amdgcn_s_setprio(0);

    // rotate pipeline state
#pragma unroll
    for (int i = 0; i < 4; ++i) sfA[i] = sfB[i];
  }

  // ---- epilogue: reduce denom over quads, normalize, store ----
  float rs = (ls[0] + ls[1]) + (ls[2] + ls[3]);
  rs += __shfl_xor(rs, 16);
  rs += __shfl_xor(rs, 32);
#pragma unroll
  for (int r = 0; r < 4; ++r) {
    float dr = __shfl(rs, quad * 4 + r);
    float inv = 1.f / dr;
    int qo = qw + quad * 4 + r;
    float* op = OUT + ((size_t)b * Lc + qo) * HD + (size_t)h * Dc + col;
    op[0]  = o[0][r] * inv;
    op[16] = o[1][r] * inv;
    op[32] = o[2][r] * inv;
    op[48] = o[3][r] * inv;
  }
}

extern "C" void kernel_launch(void* const* d_in, const int* in_sizes, int n_in,
                              void* d_out, int out_size, void* d_ws, size_t ws_size,
                              hipStream_t stream) {
  const float* Q   = (const float*)d_in[0];
  const float* K   = (const float*)d_in[1];
  const float* V   = (const float*)d_in[2];
  const int*   ATT = (const int*)d_in[3];
  float* OUT = (float*)d_out;
  (void)in_sizes; (void)n_in; (void)out_size; (void)ws_size;

  const size_t NE = (size_t)Bc * Lc * Hc * Dc;
  bf16_t* Kb = (bf16_t*)d_ws;
  bf16_t* Vt = Kb + NE;

  prep_fused<<<dim3((unsigned)(PREPK_BLOCKS + Bc * Hc * (Lc / 64))), dim3(256), 0, stream>>>(K, Kb, V, Vt);
  continual_attn<<<dim3(Bc * Hc * (Lc / ROWS_BLK)), dim3(256), 0, stream>>>(Q, Kb, Vt, ATT, OUT);
}